// Round 9
// baseline (600.383 us; speedup 1.0000x reference)
//
#include <hip/hip_runtime.h>
#include <hip/hip_bf16.h>

#define B_  4
#define S_  2048
#define E_  1024
#define H_  16
#define DH_ 64
#define M_  (B_*S_)    // 8192 rows
#define HD_ (H_*DH_)   // 1024

typedef unsigned short u16;
typedef __attribute__((ext_vector_type(8))) __bf16 bf16x8;
typedef __attribute__((ext_vector_type(4))) __bf16 bf16x4;
typedef __attribute__((ext_vector_type(4))) float  f32x4;

#if __has_builtin(__builtin_amdgcn_exp2f)
#define EXP2F __builtin_amdgcn_exp2f
#else
#define EXP2F __builtin_exp2f
#endif

// softmax scale folded into Q at QKV epilogue: 1/sqrt(64) * log2(e)
#define QSCALE 0.18033688011112042f

// ---- async global->LDS, 16B per lane ----
__device__ __forceinline__ void g2l16(const void* g, void* l) {
  __builtin_amdgcn_global_load_lds(
      (const __attribute__((address_space(1))) void*)g,
      (__attribute__((address_space(3))) void*)l, 16, 0, 0);
}

// RNE float -> bf16 bits (scalar path, used in prep only)
__device__ __forceinline__ u16 f2bf(float f) {
  union { float f; unsigned u; } v; v.f = f;
  unsigned r = v.u + 0x7FFFu + ((v.u >> 16) & 1u);
  return (u16)(r >> 16);
}

__device__ __forceinline__ float bf2f(u16 u) {
  union { unsigned u; float f; } v; v.u = ((unsigned)u) << 16; return v.f;
}

// ---------------- fused prep: cvt_x | pack_wqkv | pack_wo ----------------
__global__ __launch_bounds__(256) void prep_kernel(
    const float* __restrict__ x, const float* __restrict__ Wq,
    const float* __restrict__ Wk, const float* __restrict__ Wv,
    const float* __restrict__ Wo,
    u16* __restrict__ xb, u16* __restrict__ wqkvT, u16* __restrict__ woT) {
  __shared__ u16 tile[64][66];
  const int blk = blockIdx.x, tid = threadIdx.x;
  if (blk < 8192) {
    int i = blk * 256 + tid;
    float4 v = ((const float4*)x)[i];
    ushort4 o;
    o.x = f2bf(v.x); o.y = f2bf(v.y); o.z = f2bf(v.z); o.w = f2bf(v.w);
    ((ushort4*)xb)[i] = o;
  } else if (blk < 8960) {
    int b2 = blk - 8192;
    int p = b2 >> 8, h = (b2 >> 4) & 15, e0 = (b2 & 15) * 64;
    const float* src = (p == 0 ? Wq : (p == 1 ? Wk : Wv)) + h * (E_ * DH_);
#pragma unroll
    for (int r = 0; r < 16; ++r) {
      int idx = r * 256 + tid;
      int el = idx >> 6, d = idx & 63;
      tile[el][d] = f2bf(src[(e0 + el) * DH_ + d]);
    }
    __syncthreads();
    u16* dst = wqkvT + (p * HD_ + h * DH_) * E_;
#pragma unroll
    for (int r = 0; r < 16; ++r) {
      int idx = r * 256 + tid;
      int d = idx >> 6, el = idx & 63;
      dst[d * E_ + e0 + el] = tile[el][d];
    }
  } else {
    int b3 = blk - 8960;
    int c0 = (b3 >> 4) * 64, e0 = (b3 & 15) * 64;
#pragma unroll
    for (int r = 0; r < 16; ++r) {
      int idx = r * 256 + tid;
      int cl = idx >> 6, el = idx & 63;
      tile[cl][el] = f2bf(Wo[(c0 + cl) * E_ + e0 + el]);
    }
    __syncthreads();
#pragma unroll
    for (int r = 0; r < 16; ++r) {
      int idx = r * 256 + tid;
      int er = idx >> 6, cl = idx & 63;
      woT[(e0 + er) * HD_ + c0 + cl] = tile[cl][er];
    }
  }
}

// ---------------- GEMM: C[M][N] = A[M][K] * Bt[N][K]^T, K = 1024, BK = 64 ----
// MODE 0: QKV epilogue — bias, bf16, then LDS round-trip to emit 16B coalesced
//         stores (R7 WRITE_SIZE showed 2x sector amplification from scattered
//         2B stores). Q/K in [m][cc] orientation; V written DIRECTLY as
//         V^T [b,h,d,s] via [cc][m] orientation (transpose_v kernel deleted).
// MODE 1: out-proj epilogue (b0=bo; bias + fp32 direct store)
template <int MODE>
__global__ __launch_bounds__(256) void gemm_bt_kernel(
    const u16* __restrict__ A, const u16* __restrict__ Bt,
    const float* __restrict__ b0, const float* __restrict__ b1,
    const float* __restrict__ b2,
    u16* __restrict__ oQ, u16* __restrict__ oK, u16* __restrict__ oV,
    float* __restrict__ oF) {
  constexpr int K = 1024;
  __shared__ __align__(16) u16 smem[2 * 128 * 64];   // As | Bs; reused as 128x128 C-tile
  u16* As = smem;
  u16* Bs = smem + 128 * 64;
  const int tid = threadIdx.x;
  const int lane = tid & 63, wv = tid >> 6;
  const int wm = (wv >> 1) * 64, wn = (wv & 1) * 64;
  const int q4 = lane >> 4, lm = lane & 15;
  const int tileM = blockIdx.y * 128, tileN = blockIdx.x * 128;

  const u16* gA[4]; const u16* gB[4]; u16* lA[4]; u16* lB[4];
#pragma unroll
  for (int rr = 0; rr < 4; ++rr) {
    int c = rr * 256 + tid;
    int r = c >> 3, sw = ((c & 7) ^ (r & 7)) * 8;
    gA[rr] = A + (size_t)(tileM + r) * K + sw;
    gB[rr] = Bt + (size_t)(tileN + r) * K + sw;
    lA[rr] = As + c * 8;
    lB[rr] = Bs + c * 8;
  }

  f32x4 acc[4][4] = {};

  int aoff[2][4], boff[2][4];
#pragma unroll
  for (int ks = 0; ks < 2; ++ks) {
#pragma unroll
    for (int i = 0; i < 4; ++i) {
      int ra = wm + i * 16 + lm;
      aoff[ks][i] = ra * 64 + (((ks * 4 + q4) ^ (ra & 7)) * 8);
      int rb = wn + i * 16 + lm;
      boff[ks][i] = rb * 64 + (((ks * 4 + q4) ^ (rb & 7)) * 8);
    }
  }

  for (int k0 = 0; k0 < K; k0 += 64) {
#pragma unroll
    for (int rr = 0; rr < 4; ++rr) {
      g2l16(gA[rr] + k0, lA[rr]);
      g2l16(gB[rr] + k0, lB[rr]);
    }
    __syncthreads();
#pragma unroll
    for (int ks = 0; ks < 2; ++ks) {
      bf16x8 af[4], bf[4];
#pragma unroll
      for (int i = 0; i < 4; ++i) af[i] = *(const bf16x8*)(As + aoff[ks][i]);
#pragma unroll
      for (int j = 0; j < 4; ++j) bf[j] = *(const bf16x8*)(Bs + boff[ks][j]);
#pragma unroll
      for (int i = 0; i < 4; ++i)
#pragma unroll
        for (int j = 0; j < 4; ++j)
          acc[i][j] = __builtin_amdgcn_mfma_f32_16x16x32_bf16(af[i], bf[j], acc[i][j], 0, 0, 0);
    }
    __syncthreads();
  }

  if (MODE == 1) {
#pragma unroll
    for (int j = 0; j < 4; ++j) {
      int n = tileN + wn + j * 16 + lm;
      float bs = b0[n];
#pragma unroll
      for (int i = 0; i < 4; ++i) {
        int m0 = tileM + wm + i * 16 + q4 * 4;
#pragma unroll
        for (int r = 0; r < 4; ++r) oF[(m0 + r) * HD_ + n] = acc[i][j][r] + bs;
      }
    }
  } else {
    // ---- LDS round-trip epilogue (after final barrier, smem is free) ----
    u16* TT = smem;                        // 128 x 128 bf16, swizzled
    const int ccb = tileN & 1023;
    const int proj = tileN >> 10;          // uniform per block
    const float scl = (proj == 0 ? QSCALE : 1.0f);
    const float* bp = (proj == 0 ? b0 : (proj == 1 ? b1 : b2));
#pragma unroll
    for (int j = 0; j < 4; ++j) {
      int ncl = wn + j * 16 + lm;
      float bs = bp[ccb + ncl];
#pragma unroll
      for (int i = 0; i < 4; ++i) {
        int m0 = wm + i * 16 + q4 * 4;
        f32x4 vv;
#pragma unroll
        for (int r = 0; r < 4; ++r) vv[r] = (acc[i][j][r] + bs) * scl;
        bf16x4 ov = __builtin_convertvector(vv, bf16x4);
        if (proj < 2) {
          // orientation A: element (ml, ccl) at ml*128 + (ccl ^ 8*(ml&15))
          ushort4 us = *(ushort4*)&ov;
          TT[(m0 + 0) * 128 + (ncl ^ (8 * ((m0 + 0) & 15)))] = us.x;
          TT[(m0 + 1) * 128 + (ncl ^ (8 * ((m0 + 1) & 15)))] = us.y;
          TT[(m0 + 2) * 128 + (ncl ^ (8 * ((m0 + 2) & 15)))] = us.z;
          TT[(m0 + 3) * 128 + (ncl ^ (8 * ((m0 + 3) & 15)))] = us.w;
        } else {
          // orientation B: element (ccl, ml) at ccl*128 + (ml ^ 8*(ccl&15))
          *(bf16x4*)(TT + ncl * 128 + (m0 ^ (8 * (ncl & 15)))) = ov;  // b64
        }
      }
    }
    __syncthreads();
    if (proj < 2) {
      u16* optr = (proj == 0 ? oQ : oK);
#pragma unroll
      for (int rr = 0; rr < 8; ++rr) {
        int seg = rr * 256 + tid;
        int ml = seg >> 4, sc = (seg & 15) * 8;
        uint4 val = *(const uint4*)(TT + ml * 128 + (sc ^ (8 * (ml & 15))));
        *(uint4*)(optr + (size_t)(tileM + ml) * 1024 + ccb + sc) = val;
      }
    } else {
      const int bb = tileM >> 11, s0 = tileM & 2047;
#pragma unroll
      for (int rr = 0; rr < 8; ++rr) {
        int seg = rr * 256 + tid;
        int ccl = seg >> 4, sc = (seg & 15) * 8;
        int cc = ccb + ccl;
        int hh = cc >> 6, dd = cc & 63;
        uint4 val = *(const uint4*)(TT + ccl * 128 + (sc ^ (8 * (ccl & 15))));
        *(uint4*)(oV + ((size_t)(bb * 16 + hh) * 64 + dd) * 2048 + s0 + sc) = val;
      }
    }
  }
}

// ---------------- flash attention, split-K over key range ----------------
// grid 1024: bh = bid>>4, qt = (bid>>1)&7, split = bid&1 (16 key-tiles each).
// 4 blocks/CU (launch_bounds (256,4); VGPR demand ~108 < 128 cap, no spills).
// Writes UNNORMALIZED partial O (bf16) + li (fp32); combine_kernel finishes.
// Key-permutation trick (R5): S^T-MFMA output IS the PV A-frag layout.
__global__ __launch_bounds__(256, 4) void flash_kernel(
    const u16* __restrict__ Q, const u16* __restrict__ Kb,
    const u16* __restrict__ Vt,
    u16* __restrict__ O0, u16* __restrict__ O1, float* __restrict__ liW) {
  __shared__ __align__(16) u16 Ks[2][64 * 64];   // [slot][d] swizzled, key-permuted
  __shared__ __align__(16) u16 Vs[2][64 * 64];   // [d][key] swizzled, sequential
  const int tid = threadIdx.x, lane = tid & 63, wv = tid >> 6;
  const int q4 = lane >> 4, lm = lane & 15;

  const int bid = blockIdx.x;
  const int bh = bid >> 4, qt = (bid >> 1) & 7, sp = bid & 1;
  const int b = bh >> 4, h = bh & 15;
  const int tbase = sp * 16;                     // first key-tile of this split

  const u16* qbase = Q + ((size_t)(b * S_ + qt * 256)) * HD_ + h * DH_;
  const u16* kbase = Kb + (size_t)b * S_ * HD_ + h * DH_;
  const u16* vbase = Vt + ((size_t)(b * H_ + h)) * DH_ * S_;
  u16* obase = (sp ? O1 : O0) + ((size_t)(b * S_ + qt * 256)) * HD_ + h * DH_;
  float* libase = liW + sp * (64 * 2048) + bh * 2048 + qt * 256;

  const int c0 = tid,       r0 = c0 >> 3, s0 = ((c0 & 7) ^ (r0 & 7)) * 8;
  const int c1 = tid + 256, r1 = c1 >> 3, s1 = ((c1 & 7) ^ (r1 & 7)) * 8;
  const int kr0 = ((r0 >> 4) & 1) * 32 + ((r0 >> 2) & 3) * 8 + (r0 >> 5) * 4 + (r0 & 3);
  const int kr1 = ((r1 >> 4) & 1) * 32 + ((r1 >> 2) & 3) * 8 + (r1 >> 5) * 4 + (r1 & 3);

  bf16x8 qf[4][2];
#pragma unroll
  for (int qs = 0; qs < 4; ++qs)
#pragma unroll
    for (int dc = 0; dc < 2; ++dc)
      qf[qs][dc] = *(const bf16x8*)(qbase + (wv * 64 + qs * 16 + lm) * HD_ + dc * 32 + q4 * 8);

  const bf16x8 ones = {(__bf16)1.f, (__bf16)1.f, (__bf16)1.f, (__bf16)1.f,
                       (__bf16)1.f, (__bf16)1.f, (__bf16)1.f, (__bf16)1.f};

  int koff[4][2], voff[2][4];
#pragma unroll
  for (int kb = 0; kb < 4; ++kb)
#pragma unroll
    for (int dc = 0; dc < 2; ++dc) {
      int row = kb * 16 + lm;
      koff[kb][dc] = row * 64 + (((dc * 4 + q4) ^ (row & 7)) * 8);
    }
#pragma unroll
  for (int ck = 0; ck < 2; ++ck)
#pragma unroll
    for (int db = 0; db < 4; ++db) {
      int row = db * 16 + lm;
      voff[ck][db] = row * 64 + (((ck * 4 + q4) ^ (row & 7)) * 8);
    }

  f32x4 oacc[4][4] = {};
  f32x4 liacc[4] = {};

  {
    const u16* kt = kbase + (size_t)tbase * 64 * HD_;
    const u16* vt = vbase + tbase * 64;
    g2l16(kt + kr0 * HD_ + s0, Ks[0] + c0 * 8);
    g2l16(kt + kr1 * HD_ + s1, Ks[0] + c1 * 8);
    g2l16(vt + r0 * S_ + s0, Vs[0] + c0 * 8);
    g2l16(vt + r1 * S_ + s1, Vs[0] + c1 * 8);
  }

  for (int t = 0; t < 16; ++t) {
    const int pb = t & 1;
    __syncthreads();
    if (t < 15) {
      const u16* kt = kbase + (size_t)(tbase + t + 1) * 64 * HD_;
      const u16* vt = vbase + (tbase + t + 1) * 64;
      g2l16(kt + kr0 * HD_ + s0, Ks[1 - pb] + c0 * 8);
      g2l16(kt + kr1 * HD_ + s1, Ks[1 - pb] + c1 * 8);
      g2l16(vt + r0 * S_ + s0, Vs[1 - pb] + c0 * 8);
      g2l16(vt + r1 * S_ + s1, Vs[1 - pb] + c1 * 8);
    }
    const u16* Kp = Ks[pb];
    const u16* Vp = Vs[pb];

#pragma unroll
    for (int ck = 0; ck < 2; ++ck) {
      bf16x8 ka0 = *(const bf16x8*)(Kp + koff[ck][0]);
      bf16x8 ka1 = *(const bf16x8*)(Kp + koff[ck][1]);
      bf16x8 kb0 = *(const bf16x8*)(Kp + koff[ck + 2][0]);
      bf16x8 kb1 = *(const bf16x8*)(Kp + koff[ck + 2][1]);
      bf16x8 pf[4];
#pragma unroll
      for (int qs = 0; qs < 4; ++qs) {
        f32x4 sa = {}, sb = {};
        sa = __builtin_amdgcn_mfma_f32_16x16x32_bf16(ka0, qf[qs][0], sa, 0, 0, 0);
        sa = __builtin_amdgcn_mfma_f32_16x16x32_bf16(ka1, qf[qs][1], sa, 0, 0, 0);
        sb = __builtin_amdgcn_mfma_f32_16x16x32_bf16(kb0, qf[qs][0], sb, 0, 0, 0);
        sb = __builtin_amdgcn_mfma_f32_16x16x32_bf16(kb1, qf[qs][1], sb, 0, 0, 0);
        f32x4 pa, pb2;
#pragma unroll
        for (int r = 0; r < 4; ++r) { pa[r] = EXP2F(sa[r]); pb2[r] = EXP2F(sb[r]); }
        bf16x4 la = __builtin_convertvector(pa, bf16x4);
        bf16x4 lb = __builtin_convertvector(pb2, bf16x4);
        pf[qs] = __builtin_shufflevector(la, lb, 0, 1, 2, 3, 4, 5, 6, 7);
      }
#pragma unroll
      for (int qs = 0; qs < 4; ++qs)
        liacc[qs] = __builtin_amdgcn_mfma_f32_16x16x32_bf16(pf[qs], ones, liacc[qs], 0, 0, 0);
#pragma unroll
      for (int db = 0; db < 4; ++db) {
        bf16x8 vf = *(const bf16x8*)(Vp + voff[ck][db]);
#pragma unroll
        for (int qs = 0; qs < 4; ++qs)
          oacc[qs][db] = __builtin_amdgcn_mfma_f32_16x16x32_bf16(pf[qs], vf, oacc[qs][db], 0, 0, 0);
      }
    }
  }

  // ---- store unnormalized partial O (bf16) + li (fp32) ----
#pragma unroll
  for (int qs = 0; qs < 4; ++qs) {
#pragma unroll
    for (int db = 0; db < 4; ++db) {
      bf16x4 ov = __builtin_convertvector(oacc[qs][db], bf16x4);
      ushort4 us = *(ushort4*)&ov;
      int m0 = wv * 64 + qs * 16 + q4 * 4;
      obase[(m0 + 0) * HD_ + db * 16 + lm] = us.x;
      obase[(m0 + 1) * HD_ + db * 16 + lm] = us.y;
      obase[(m0 + 2) * HD_ + db * 16 + lm] = us.z;
      obase[(m0 + 3) * HD_ + db * 16 + lm] = us.w;
    }
  }
  if (lm == 0) {
#pragma unroll
    for (int qs = 0; qs < 4; ++qs)
#pragma unroll
      for (int r = 0; r < 4; ++r)
        libase[wv * 64 + qs * 16 + q4 * 4 + r] = liacc[qs][r];
  }
}

// ---------------- combine: z = (o1 + o2) / (l1 + l2), in place over o2 ----
__global__ __launch_bounds__(256) void combine_kernel(
    const u16* __restrict__ o1, u16* o2z, const float* __restrict__ li) {
  const int tid = threadIdx.x;
  const int row = blockIdx.x * 2 + (tid >> 7);
  const int c0 = (tid & 127) * 8;
  const int bh = (row >> 11) * 16 + (c0 >> 6);
  const int s = row & 2047;
  const float l = li[bh * 2048 + s] + li[64 * 2048 + bh * 2048 + s];
  const float rin = 1.f / l;
  const size_t off = (size_t)row * 1024 + c0;
  ushort4 a0 = *(const ushort4*)(o1 + off);
  ushort4 a1 = *(const ushort4*)(o1 + off + 4);
  ushort4 b0 = *(const ushort4*)(o2z + off);
  ushort4 b1 = *(const ushort4*)(o2z + off + 4);
  f32x4 v0, v1;
  v0[0] = (bf2f(a0.x) + bf2f(b0.x)) * rin;
  v0[1] = (bf2f(a0.y) + bf2f(b0.y)) * rin;
  v0[2] = (bf2f(a0.z) + bf2f(b0.z)) * rin;
  v0[3] = (bf2f(a0.w) + bf2f(b0.w)) * rin;
  v1[0] = (bf2f(a1.x) + bf2f(b1.x)) * rin;
  v1[1] = (bf2f(a1.y) + bf2f(b1.y)) * rin;
  v1[2] = (bf2f(a1.z) + bf2f(b1.z)) * rin;
  v1[3] = (bf2f(a1.w) + bf2f(b1.w)) * rin;
  bf16x4 z0 = __builtin_convertvector(v0, bf16x4);
  bf16x4 z1 = __builtin_convertvector(v1, bf16x4);
  *(bf16x4*)(o2z + off) = z0;
  *(bf16x4*)(o2z + off + 4) = z1;
}

// ---------------- host ----------------
extern "C" void kernel_launch(void* const* d_in, const int* in_sizes, int n_in,
                              void* d_out, int out_size, void* d_ws, size_t ws_size,
                              hipStream_t stream) {
  const float* x  = (const float*)d_in[0];
  const float* Wq = (const float*)d_in[1];
  const float* bq = (const float*)d_in[2];
  const float* Wk = (const float*)d_in[3];
  const float* bk = (const float*)d_in[4];
  const float* Wv = (const float*)d_in[5];
  const float* bv = (const float*)d_in[6];
  const float* Wo = (const float*)d_in[7];
  const float* bo = (const float*)d_in[8];
  float* out = (float*)d_out;

  char* w = (char*)d_ws;
  u16*   xb    = (u16*)w;   w += (size_t)M_ * E_ * 2;      // 16 MB; o1 after gemm0
  u16*   wqkvT = (u16*)w;   w += (size_t)3 * HD_ * E_ * 2; //  6 MB; liW after gemm0
  u16*   woT   = (u16*)w;   w += (size_t)E_ * HD_ * 2;     //  2 MB
  u16*   qB    = (u16*)w;   w += (size_t)M_ * HD_ * 2;
  u16*   kB    = (u16*)w;   w += (size_t)M_ * HD_ * 2;
  u16*   vT    = (u16*)w;   w += (size_t)M_ * HD_ * 2;     // V^T written by gemm0
  u16*   zB    = (u16*)w;   w += (size_t)M_ * HD_ * 2;     // o2, combined in place
  u16*   o1    = xb;          // dead after gemm0
  float* liW   = (float*)wqkvT;  // dead after gemm0 (needs 1 MB)

  prep_kernel<<<dim3(9216), 256, 0, stream>>>(x, Wq, Wk, Wv, Wo, xb, wqkvT, woT);
  gemm_bt_kernel<0><<<dim3(24, 64), 256, 0, stream>>>(xb, wqkvT, bq, bk, bv,
                                                      qB, kB, vT, nullptr);
  flash_kernel<<<dim3(1024), 256, 0, stream>>>(qB, kB, vT, o1, zB, liW);
  combine_kernel<<<dim3(4096), 256, 0, stream>>>(o1, zB, liW);
  gemm_bt_kernel<1><<<dim3(8, 64), 256, 0, stream>>>(zB, woT, bo, nullptr, nullptr,
                                                     nullptr, nullptr, nullptr, out);
}

// Round 10
// 259.837 us; speedup vs baseline: 2.3106x; 2.3106x over previous
//
#include <hip/hip_runtime.h>
#include <hip/hip_bf16.h>

#define B_  4
#define S_  2048
#define E_  1024
#define H_  16
#define DH_ 64
#define M_  (B_*S_)    // 8192 rows
#define HD_ (H_*DH_)   // 1024

typedef unsigned short u16;
typedef __attribute__((ext_vector_type(8))) __bf16 bf16x8;
typedef __attribute__((ext_vector_type(4))) __bf16 bf16x4;
typedef __attribute__((ext_vector_type(4))) float  f32x4;

#if __has_builtin(__builtin_amdgcn_exp2f)
#define EXP2F __builtin_amdgcn_exp2f
#else
#define EXP2F __builtin_exp2f
#endif

// softmax scale folded into Q at QKV epilogue: 1/sqrt(64) * log2(e)
#define QSCALE 0.18033688011112042f

// ---- async global->LDS, 16B per lane ----
__device__ __forceinline__ void g2l16(const void* g, void* l) {
  __builtin_amdgcn_global_load_lds(
      (const __attribute__((address_space(1))) void*)g,
      (__attribute__((address_space(3))) void*)l, 16, 0, 0);
}

// RNE float -> bf16 bits (scalar path, used in prep only)
__device__ __forceinline__ u16 f2bf(float f) {
  union { float f; unsigned u; } v; v.f = f;
  unsigned r = v.u + 0x7FFFu + ((v.u >> 16) & 1u);
  return (u16)(r >> 16);
}

// ---------------- fused prep: cvt_x | pack_wqkv | pack_wo ----------------
__global__ __launch_bounds__(256) void prep_kernel(
    const float* __restrict__ x, const float* __restrict__ Wq,
    const float* __restrict__ Wk, const float* __restrict__ Wv,
    const float* __restrict__ Wo,
    u16* __restrict__ xb, u16* __restrict__ wqkvT, u16* __restrict__ woT) {
  __shared__ u16 tile[64][66];
  const int blk = blockIdx.x, tid = threadIdx.x;
  if (blk < 8192) {
    int i = blk * 256 + tid;
    float4 v = ((const float4*)x)[i];
    ushort4 o;
    o.x = f2bf(v.x); o.y = f2bf(v.y); o.z = f2bf(v.z); o.w = f2bf(v.w);
    ((ushort4*)xb)[i] = o;
  } else if (blk < 8960) {
    int b2 = blk - 8192;
    int p = b2 >> 8, h = (b2 >> 4) & 15, e0 = (b2 & 15) * 64;
    const float* src = (p == 0 ? Wq : (p == 1 ? Wk : Wv)) + h * (E_ * DH_);
#pragma unroll
    for (int r = 0; r < 16; ++r) {
      int idx = r * 256 + tid;
      int el = idx >> 6, d = idx & 63;
      tile[el][d] = f2bf(src[(e0 + el) * DH_ + d]);
    }
    __syncthreads();
    u16* dst = wqkvT + (p * HD_ + h * DH_) * E_;
#pragma unroll
    for (int r = 0; r < 16; ++r) {
      int idx = r * 256 + tid;
      int d = idx >> 6, el = idx & 63;
      dst[d * E_ + e0 + el] = tile[el][d];
    }
  } else {
    int b3 = blk - 8960;
    int c0 = (b3 >> 4) * 64, e0 = (b3 & 15) * 64;
#pragma unroll
    for (int r = 0; r < 16; ++r) {
      int idx = r * 256 + tid;
      int cl = idx >> 6, el = idx & 63;
      tile[cl][el] = f2bf(Wo[(c0 + cl) * E_ + e0 + el]);
    }
    __syncthreads();
#pragma unroll
    for (int r = 0; r < 16; ++r) {
      int idx = r * 256 + tid;
      int er = idx >> 6, cl = idx & 63;
      woT[(e0 + er) * HD_ + c0 + cl] = tile[cl][er];
    }
  }
}

// ---------------- GEMM: C[M][N] = A[M][K] * Bt[N][K]^T, K = 1024, BK = 64 ----
// MODE 0: QKV epilogue — bias, bf16, then LDS round-trip to emit 16B coalesced
//         stores. Q/K in [m][cc] orientation; V written DIRECTLY as V^T
//         [b,h,d,s] via [cc][m] orientation (no separate transpose kernel).
// MODE 1: out-proj epilogue (b0=bo; bias + fp32 direct store)
template <int MODE>
__global__ __launch_bounds__(256) void gemm_bt_kernel(
    const u16* __restrict__ A, const u16* __restrict__ Bt,
    const float* __restrict__ b0, const float* __restrict__ b1,
    const float* __restrict__ b2,
    u16* __restrict__ oQ, u16* __restrict__ oK, u16* __restrict__ oV,
    float* __restrict__ oF) {
  constexpr int K = 1024;
  __shared__ __align__(16) u16 smem[2 * 128 * 64];   // As | Bs; reused as C-tile
  u16* As = smem;
  u16* Bs = smem + 128 * 64;
  const int tid = threadIdx.x;
  const int lane = tid & 63, wv = tid >> 6;
  const int wm = (wv >> 1) * 64, wn = (wv & 1) * 64;
  const int q4 = lane >> 4, lm = lane & 15;
  const int tileM = blockIdx.y * 128, tileN = blockIdx.x * 128;

  const u16* gA[4]; const u16* gB[4]; u16* lA[4]; u16* lB[4];
#pragma unroll
  for (int rr = 0; rr < 4; ++rr) {
    int c = rr * 256 + tid;
    int r = c >> 3, sw = ((c & 7) ^ (r & 7)) * 8;
    gA[rr] = A + (size_t)(tileM + r) * K + sw;
    gB[rr] = Bt + (size_t)(tileN + r) * K + sw;
    lA[rr] = As + c * 8;
    lB[rr] = Bs + c * 8;
  }

  f32x4 acc[4][4] = {};

  int aoff[2][4], boff[2][4];
#pragma unroll
  for (int ks = 0; ks < 2; ++ks) {
#pragma unroll
    for (int i = 0; i < 4; ++i) {
      int ra = wm + i * 16 + lm;
      aoff[ks][i] = ra * 64 + (((ks * 4 + q4) ^ (ra & 7)) * 8);
      int rb = wn + i * 16 + lm;
      boff[ks][i] = rb * 64 + (((ks * 4 + q4) ^ (rb & 7)) * 8);
    }
  }

  for (int k0 = 0; k0 < K; k0 += 64) {
#pragma unroll
    for (int rr = 0; rr < 4; ++rr) {
      g2l16(gA[rr] + k0, lA[rr]);
      g2l16(gB[rr] + k0, lB[rr]);
    }
    __syncthreads();
#pragma unroll
    for (int ks = 0; ks < 2; ++ks) {
      bf16x8 af[4], bf[4];
#pragma unroll
      for (int i = 0; i < 4; ++i) af[i] = *(const bf16x8*)(As + aoff[ks][i]);
#pragma unroll
      for (int j = 0; j < 4; ++j) bf[j] = *(const bf16x8*)(Bs + boff[ks][j]);
#pragma unroll
      for (int i = 0; i < 4; ++i)
#pragma unroll
        for (int j = 0; j < 4; ++j)
          acc[i][j] = __builtin_amdgcn_mfma_f32_16x16x32_bf16(af[i], bf[j], acc[i][j], 0, 0, 0);
    }
    __syncthreads();
  }

  if (MODE == 1) {
#pragma unroll
    for (int j = 0; j < 4; ++j) {
      int n = tileN + wn + j * 16 + lm;
      float bs = b0[n];
#pragma unroll
      for (int i = 0; i < 4; ++i) {
        int m0 = tileM + wm + i * 16 + q4 * 4;
#pragma unroll
        for (int r = 0; r < 4; ++r) oF[(m0 + r) * HD_ + n] = acc[i][j][r] + bs;
      }
    }
  } else {
    // ---- LDS round-trip epilogue (after final barrier, smem is free) ----
    u16* TT = smem;                        // 128 x 128 bf16, swizzled
    const int ccb = tileN & 1023;
    const int proj = tileN >> 10;          // uniform per block
    const float scl = (proj == 0 ? QSCALE : 1.0f);
    const float* bp = (proj == 0 ? b0 : (proj == 1 ? b1 : b2));
#pragma unroll
    for (int j = 0; j < 4; ++j) {
      int ncl = wn + j * 16 + lm;
      float bs = bp[ccb + ncl];
#pragma unroll
      for (int i = 0; i < 4; ++i) {
        int m0 = wm + i * 16 + q4 * 4;
        f32x4 vv;
#pragma unroll
        for (int r = 0; r < 4; ++r) vv[r] = (acc[i][j][r] + bs) * scl;
        bf16x4 ov = __builtin_convertvector(vv, bf16x4);
        if (proj < 2) {
          // orientation A: element (ml, ccl) at ml*128 + (ccl ^ 8*(ml&15))
          ushort4 us = *(ushort4*)&ov;
          TT[(m0 + 0) * 128 + (ncl ^ (8 * ((m0 + 0) & 15)))] = us.x;
          TT[(m0 + 1) * 128 + (ncl ^ (8 * ((m0 + 1) & 15)))] = us.y;
          TT[(m0 + 2) * 128 + (ncl ^ (8 * ((m0 + 2) & 15)))] = us.z;
          TT[(m0 + 3) * 128 + (ncl ^ (8 * ((m0 + 3) & 15)))] = us.w;
        } else {
          // orientation B: element (ccl, ml) at ccl*128 + (ml ^ 8*(ccl&15))
          *(bf16x4*)(TT + ncl * 128 + (m0 ^ (8 * (ncl & 15)))) = ov;  // b64
        }
      }
    }
    __syncthreads();
    if (proj < 2) {
      u16* optr = (proj == 0 ? oQ : oK);
#pragma unroll
      for (int rr = 0; rr < 8; ++rr) {
        int seg = rr * 256 + tid;
        int ml = seg >> 4, sc = (seg & 15) * 8;
        uint4 val = *(const uint4*)(TT + ml * 128 + (sc ^ (8 * (ml & 15))));
        *(uint4*)(optr + (size_t)(tileM + ml) * 1024 + ccb + sc) = val;
      }
    } else {
      const int bb = tileM >> 11, s0 = tileM & 2047;
#pragma unroll
      for (int rr = 0; rr < 8; ++rr) {
        int seg = rr * 256 + tid;
        int ccl = seg >> 4, sc = (seg & 15) * 8;
        int cc = ccb + ccl;
        int hh = cc >> 6, dd = cc & 63;
        uint4 val = *(const uint4*)(TT + ccl * 128 + (sc ^ (8 * (ccl & 15))));
        *(uint4*)(oV + ((size_t)(bb * 16 + hh) * 64 + dd) * 2048 + s0 + sc) = val;
      }
    }
  }
}

// ---------------- flash attention (R8 proven config) ----------------
// Block: 256 q-rows of one (b,h); wave wv owns q-rows [wv*64, wv*64+64), all keys.
// K/V double-buffered in LDS via global_load_lds (one barrier per tile).
// KEY PERMUTATION: K rows staged at LDS slot s = kb*16+q4*4+r hold logical key
// kperm(s) = (kb&1)*32 + q4*8 + (kb>>1)*4 + r. The S^T-MFMA C-layout output IS
// the PV A-fragment layout per-lane; V keeps sequential key order. P never
// touches LDS.
// REGISTER RULE (R6, R9 failures): unified VGPR+AGPR demand is ~170+; any
// launch_bounds tighter than (256,2) forces a spill storm (WRITE_SIZE blows
// up to ~0.5-1.2 GB, 3-5x slowdown). Keep (256,2). Do not split-K.
__global__ __launch_bounds__(256, 2) void flash_kernel(
    const u16* __restrict__ Q, const u16* __restrict__ Kb,
    const u16* __restrict__ Vt, u16* __restrict__ Z) {
  __shared__ __align__(16) u16 Ks[2][64 * 64];   // [slot][d] swizzled, key-permuted
  __shared__ __align__(16) u16 Vs[2][64 * 64];   // [d][key] swizzled, sequential
  const int tid = threadIdx.x, lane = tid & 63, wv = tid >> 6;
  const int q4 = lane >> 4, lm = lane & 15;

  const int bid = blockIdx.x;
  const int bh = bid >> 3, qt = bid & 7;         // 8 consecutive blocks share (b,h) K/V
  const int b = bh >> 4, h = bh & 15;

  const u16* qbase = Q + ((size_t)(b * S_ + qt * 256)) * HD_ + h * DH_;
  const u16* kbase = Kb + (size_t)b * S_ * HD_ + h * DH_;
  const u16* vbase = Vt + ((size_t)(b * H_ + h)) * DH_ * S_;
  u16* zbase = Z + ((size_t)(b * S_ + qt * 256)) * HD_ + h * DH_;

  const int c0 = tid,       r0 = c0 >> 3, s0 = ((c0 & 7) ^ (r0 & 7)) * 8;
  const int c1 = tid + 256, r1 = c1 >> 3, s1 = ((c1 & 7) ^ (r1 & 7)) * 8;
  const int kr0 = ((r0 >> 4) & 1) * 32 + ((r0 >> 2) & 3) * 8 + (r0 >> 5) * 4 + (r0 & 3);
  const int kr1 = ((r1 >> 4) & 1) * 32 + ((r1 >> 2) & 3) * 8 + (r1 >> 5) * 4 + (r1 & 3);

  bf16x8 qf[4][2];
#pragma unroll
  for (int qs = 0; qs < 4; ++qs)
#pragma unroll
    for (int dc = 0; dc < 2; ++dc)
      qf[qs][dc] = *(const bf16x8*)(qbase + (wv * 64 + qs * 16 + lm) * HD_ + dc * 32 + q4 * 8);

  const bf16x8 ones = {(__bf16)1.f, (__bf16)1.f, (__bf16)1.f, (__bf16)1.f,
                       (__bf16)1.f, (__bf16)1.f, (__bf16)1.f, (__bf16)1.f};

  int koff[4][2], voff[2][4];
#pragma unroll
  for (int kb = 0; kb < 4; ++kb)
#pragma unroll
    for (int dc = 0; dc < 2; ++dc) {
      int row = kb * 16 + lm;
      koff[kb][dc] = row * 64 + (((dc * 4 + q4) ^ (row & 7)) * 8);
    }
#pragma unroll
  for (int ck = 0; ck < 2; ++ck)
#pragma unroll
    for (int db = 0; db < 4; ++db) {
      int row = db * 16 + lm;
      voff[ck][db] = row * 64 + (((ck * 4 + q4) ^ (row & 7)) * 8);
    }

  f32x4 oacc[4][4] = {};
  f32x4 liacc[4] = {};

  {
    g2l16(kbase + kr0 * HD_ + s0, Ks[0] + c0 * 8);
    g2l16(kbase + kr1 * HD_ + s1, Ks[0] + c1 * 8);
    g2l16(vbase + r0 * S_ + s0, Vs[0] + c0 * 8);
    g2l16(vbase + r1 * S_ + s1, Vs[0] + c1 * 8);
  }

  for (int t = 0; t < 32; ++t) {
    const int pb = t & 1;
    __syncthreads();
    if (t < 31) {
      const u16* kt = kbase + (size_t)(t + 1) * 64 * HD_;
      const u16* vt = vbase + (t + 1) * 64;
      g2l16(kt + kr0 * HD_ + s0, Ks[1 - pb] + c0 * 8);
      g2l16(kt + kr1 * HD_ + s1, Ks[1 - pb] + c1 * 8);
      g2l16(vt + r0 * S_ + s0, Vs[1 - pb] + c0 * 8);
      g2l16(vt + r1 * S_ + s1, Vs[1 - pb] + c1 * 8);
    }
    const u16* Kp = Ks[pb];
    const u16* Vp = Vs[pb];

#pragma unroll
    for (int ck = 0; ck < 2; ++ck) {
      bf16x8 ka0 = *(const bf16x8*)(Kp + koff[ck][0]);
      bf16x8 ka1 = *(const bf16x8*)(Kp + koff[ck][1]);
      bf16x8 kb0 = *(const bf16x8*)(Kp + koff[ck + 2][0]);
      bf16x8 kb1 = *(const bf16x8*)(Kp + koff[ck + 2][1]);
      bf16x8 pf[4];
#pragma unroll
      for (int qs = 0; qs < 4; ++qs) {
        f32x4 sa = {}, sb = {};
        sa = __builtin_amdgcn_mfma_f32_16x16x32_bf16(ka0, qf[qs][0], sa, 0, 0, 0);
        sa = __builtin_amdgcn_mfma_f32_16x16x32_bf16(ka1, qf[qs][1], sa, 0, 0, 0);
        sb = __builtin_amdgcn_mfma_f32_16x16x32_bf16(kb0, qf[qs][0], sb, 0, 0, 0);
        sb = __builtin_amdgcn_mfma_f32_16x16x32_bf16(kb1, qf[qs][1], sb, 0, 0, 0);
        f32x4 pa, pb2;
#pragma unroll
        for (int r = 0; r < 4; ++r) { pa[r] = EXP2F(sa[r]); pb2[r] = EXP2F(sb[r]); }
        bf16x4 la = __builtin_convertvector(pa, bf16x4);
        bf16x4 lb = __builtin_convertvector(pb2, bf16x4);
        pf[qs] = __builtin_shufflevector(la, lb, 0, 1, 2, 3, 4, 5, 6, 7);
      }
#pragma unroll
      for (int qs = 0; qs < 4; ++qs)
        liacc[qs] = __builtin_amdgcn_mfma_f32_16x16x32_bf16(pf[qs], ones, liacc[qs], 0, 0, 0);
#pragma unroll
      for (int db = 0; db < 4; ++db) {
        bf16x8 vf = *(const bf16x8*)(Vp + voff[ck][db]);
#pragma unroll
        for (int qs = 0; qs < 4; ++qs)
          oacc[qs][db] = __builtin_amdgcn_mfma_f32_16x16x32_bf16(pf[qs], vf, oacc[qs][db], 0, 0, 0);
      }
    }
  }

  // ---- normalize + store (wave owns its 64 q-rows; li is in-lane) ----
#pragma unroll
  for (int qs = 0; qs < 4; ++qs) {
    float rin[4];
#pragma unroll
    for (int r = 0; r < 4; ++r) rin[r] = 1.f / liacc[qs][r];
#pragma unroll
    for (int db = 0; db < 4; ++db) {
      f32x4 vv;
#pragma unroll
      for (int r = 0; r < 4; ++r) vv[r] = oacc[qs][db][r] * rin[r];
      bf16x4 ov = __builtin_convertvector(vv, bf16x4);
      ushort4 us = *(ushort4*)&ov;
      int m0 = wv * 64 + qs * 16 + q4 * 4;
      zbase[(m0 + 0) * HD_ + db * 16 + lm] = us.x;
      zbase[(m0 + 1) * HD_ + db * 16 + lm] = us.y;
      zbase[(m0 + 2) * HD_ + db * 16 + lm] = us.z;
      zbase[(m0 + 3) * HD_ + db * 16 + lm] = us.w;
    }
  }
}

// ---------------- host ----------------
extern "C" void kernel_launch(void* const* d_in, const int* in_sizes, int n_in,
                              void* d_out, int out_size, void* d_ws, size_t ws_size,
                              hipStream_t stream) {
  const float* x  = (const float*)d_in[0];
  const float* Wq = (const float*)d_in[1];
  const float* bq = (const float*)d_in[2];
  const float* Wk = (const float*)d_in[3];
  const float* bk = (const float*)d_in[4];
  const float* Wv = (const float*)d_in[5];
  const float* bv = (const float*)d_in[6];
  const float* Wo = (const float*)d_in[7];
  const float* bo = (const float*)d_in[8];
  float* out = (float*)d_out;

  char* w = (char*)d_ws;
  u16*   xb    = (u16*)w;   w += (size_t)M_ * E_ * 2;
  u16*   wqkvT = (u16*)w;   w += (size_t)3 * HD_ * E_ * 2;
  u16*   woT   = (u16*)w;   w += (size_t)E_ * HD_ * 2;
  u16*   qB    = (u16*)w;   w += (size_t)M_ * HD_ * 2;
  u16*   kB    = (u16*)w;   w += (size_t)M_ * HD_ * 2;
  u16*   vT    = (u16*)w;   w += (size_t)M_ * HD_ * 2;     // V^T written by gemm0
  u16*   zB    = (u16*)w;   w += (size_t)M_ * HD_ * 2;

  prep_kernel<<<dim3(9216), 256, 0, stream>>>(x, Wq, Wk, Wv, Wo, xb, wqkvT, woT);
  gemm_bt_kernel<0><<<dim3(24, 64), 256, 0, stream>>>(xb, wqkvT, bq, bk, bv,
                                                      qB, kB, vT, nullptr);
  flash_kernel<<<dim3(512), 256, 0, stream>>>(qB, kB, vT, zB);
  gemm_bt_kernel<1><<<dim3(8, 64), 256, 0, stream>>>(zB, woT, bo, nullptr, nullptr,
                                                     nullptr, nullptr, nullptr, out);
}